// Round 6
// baseline (371.191 us; speedup 1.0000x reference)
//
#include <hip/hip_runtime.h>
#include <hip/hip_cooperative_groups.h>
#include <cstddef>
#include <cstdint>

namespace cg = cooperative_groups;

// SAT layout: channel-interleaved, line-aligned: sat[(y*1026 + x)*8 + c],
// row stride 1026*8 f32 = 32832 B = 513 64B lines.
//
// ROUND 6: all five round-5 dispatches fused into ONE cooperative kernel with
// grid.sync() between phases. Rounds 0/1/5 showed the "B slot" costs ~86-94us
// regardless of structure (scattered vs contiguous instructions, 1 vs 3
// kernels, 67 vs 84 MB) => the cost is not in the B code but attached to
// dependent kernel boundaries and/or a fixed in-region cost. This kernel
// removes ALL interior boundaries. Fallback to the 5-kernel path if the
// cooperative launch is rejected.

#define SATW_PAD 1026
#define W8   8200
#define W8P  8208
#define NCH  8

#define NBAND 64
#define BROWS 16
#define CHUNK_F32 1024
#define NCHUNK 9           // 8 full chunks + tail (cols 8192..8199)
#define NUNIT (NCHUNK * NBAND)   // 576

// ============================ fused cooperative kernel ======================
__global__ __launch_bounds__(256, 2)
void fused_sat_pool(const float* __restrict__ in, const int* __restrict__ rois,
                    float* __restrict__ out, float* __restrict__ sat,
                    double* __restrict__ bsum, int n_roi) {
    cg::grid_group grid = cg::this_grid();
    const int G    = gridDim.x;
    const int g    = blockIdx.x;
    const int t    = threadIdx.x;
    const int lane = t & 63;
    const int wv   = t >> 6;

    __shared__ float lds[NCH][1024];

    // ---- P1: row prefix sums, planar in -> interleaved sat rows ------------
    for (int y = g; y < 1024; y += G) {
        for (int k = 0; k < 2; ++k) {
            const int c = wv * 2 + k;
            const float4* r4 = (const float4*)(in + ((size_t)c * 1024 + y) * 1024);
            double chunkbase = 0.0;
#pragma unroll
            for (int j = 0; j < 4; ++j) {       // 4 chunks of 256 floats
                float4 a = r4[lane + 64 * j];
                double v0 = a.x, v1 = a.y, v2 = a.z, v3 = a.w;
                double s = v0 + v1 + v2 + v3;
                double ps = s;
#pragma unroll
                for (int off = 1; off < 64; off <<= 1) {
                    double n = __shfl_up(ps, off, 64);
                    if (lane >= off) ps += n;
                }
                double base = chunkbase + ps - s;
                double p0 = base + v0, p1 = p0 + v1, p2 = p1 + v2, p3 = p2 + v3;
                ((float4*)lds[c])[lane + 64 * j] =
                    make_float4((float)p0, (float)p1, (float)p2, (float)p3);
                chunkbase += __shfl(ps, 63, 64);
            }
        }
        __syncthreads();

        float* orow = sat + (size_t)(y + 1) * W8P;
        for (int f4 = t; f4 < W8P / 4; f4 += 256) {
            int f = f4 * 4;
            float4 o;
            float* po = (float*)&o;
#pragma unroll
            for (int j = 0; j < 4; ++j) {
                int ff = f + j;
                int x = ff >> 3, c = ff & 7;
                po[j] = (x >= 1 && x <= 1024) ? lds[c][x - 1] : 0.0f;
            }
            ((float4*)orow)[f4] = o;
        }
        __syncthreads();                        // WAR guard before lds reuse
    }
    grid.sync();

    // ---- P2: band column sums (16-row bands, contiguous instructions) ------
    for (int u = g; u < NUNIT; u += G) {
        const int c = u >> 6, b = u & 63;
        const int col0 = c * CHUNK_F32 + t * 4;
        if (col0 < W8) {
            const float* p = sat + (size_t)(1 + b * BROWS) * W8P + col0;
            double s0 = 0, s1 = 0, s2 = 0, s3 = 0;
#pragma unroll
            for (int k = 0; k < BROWS; ++k) {
                float4 v = *(const float4*)(p + (size_t)k * W8P);
                s0 += v.x; s1 += v.y; s2 += v.z; s3 += v.w;
            }
            double* o = bsum + (size_t)b * W8P + col0;
            double2 lo, hi;
            lo.x = s0; lo.y = s1; hi.x = s2; hi.y = s3;
            *(double2*)o       = lo;
            *((double2*)o + 1) = hi;
        }
    }
    grid.sync();

    // ---- P3: exclusive prefix over 64 bands per column (wave units) --------
    for (int lc = g * 4 + wv; lc < 513; lc += G * 4) {
        const int rg = lane >> 3;     // band group 0..7
        const int s  = lane & 7;      // double2 slot 0..7
        const size_t base = (size_t)lc * 16 + (size_t)s * 2;

        double2 v[8];
#pragma unroll
        for (int k = 0; k < 8; ++k)
            v[k] = *(const double2*)(bsum + (size_t)(rg * 8 + k) * W8P + base);

        double i0 = 0, i1 = 0;
        double incl0[8], incl1[8];
#pragma unroll
        for (int k = 0; k < 8; ++k) {
            i0 += v[k].x; i1 += v[k].y;
            incl0[k] = i0; incl1[k] = i1;
        }
        double a0 = i0, a1 = i1;
#pragma unroll
        for (int off = 8; off <= 32; off <<= 1) {
            double u0 = __shfl_up(a0, off, 64);
            double u1 = __shfl_up(a1, off, 64);
            if (lane >= off) { a0 += u0; a1 += u1; }
        }
        const double b0 = a0 - i0, b1 = a1 - i1;
#pragma unroll
        for (int k = 0; k < 8; ++k) {
            double2 e;
            e.x = b0 + incl0[k] - v[k].x;
            e.y = b1 + incl1[k] - v[k].y;
            *(double2*)(bsum + (size_t)(rg * 8 + k) * W8P + base) = e;
        }
    }
    grid.sync();

    // ---- P4: apply band prefix, finalize SAT (band 0 zeroes row 0) ---------
    for (int u = g; u < NUNIT; u += G) {
        const int c = u >> 6, b = u & 63;
        const int col0 = c * CHUNK_F32 + t * 4;
        if (col0 < W8) {
            const double* q = bsum + (size_t)b * W8P + col0;
            double2 qlo = *(const double2*)q;
            double2 qhi = *((const double2*)q + 1);
            double a0 = qlo.x, a1 = qlo.y, a2 = qhi.x, a3 = qhi.y;

            float* p = sat + (size_t)(1 + b * BROWS) * W8P + col0;
            float4 v[BROWS];
#pragma unroll
            for (int k = 0; k < BROWS; ++k)
                v[k] = *(const float4*)(p + (size_t)k * W8P);
#pragma unroll
            for (int k = 0; k < BROWS; ++k) {
                a0 += v[k].x; a1 += v[k].y; a2 += v[k].z; a3 += v[k].w;
                *(float4*)(p + (size_t)k * W8P) =
                    make_float4((float)a0, (float)a1, (float)a2, (float)a3);
            }
            if (b == 0)
                *(float4*)(sat + col0) = make_float4(0.f, 0.f, 0.f, 0.f);
        }
    }
    grid.sync();

    // ---- P5: pool — one wave per ROI ---------------------------------------
    for (int u = g; u < (n_roi + 3) / 4; u += G) {
        const int roi = u * 4 + wv;
        if (roi < n_roi) {
            const int4 rv = ((const int4*)rois)[roi];
            int ymin = rv.x >> 5;
            int xmin = rv.y >> 5;
            int Ly   = (rv.z >> 5) + 1 - ymin;
            int Lx   = (rv.w >> 5) + 1 - xmin;

            float acc[NCH];
#pragma unroll
            for (int c = 0; c < NCH; ++c) acc[c] = 0.0f;

            if (lane < 49) {
                int by = lane / 7;
                int bx = lane - by * 7;
                int ylo = ymin + (by * Ly) / 7;
                int yhi = ymin + ((by + 1) * Ly + 6) / 7;
                int xlo = xmin + (bx * Lx) / 7;
                int xhi = xmin + ((bx + 1) * Lx + 6) / 7;
                float inv = 1.0f / (float)((yhi - ylo) * (xhi - xlo));

                float4 a[2], b[2], c4[2], d[2];
                const float4* hh = (const float4*)(sat + ((size_t)yhi * SATW_PAD + xhi) * NCH);
                const float4* lh = (const float4*)(sat + ((size_t)ylo * SATW_PAD + xhi) * NCH);
                const float4* hl = (const float4*)(sat + ((size_t)yhi * SATW_PAD + xlo) * NCH);
                const float4* ll = (const float4*)(sat + ((size_t)ylo * SATW_PAD + xlo) * NCH);
                a[0] = hh[0]; a[1] = hh[1];
                b[0] = lh[0]; b[1] = lh[1];
                c4[0] = hl[0]; c4[1] = hl[1];
                d[0] = ll[0]; d[1] = ll[1];
                const float* fa = (const float*)a;
                const float* fb = (const float*)b;
                const float* fc = (const float*)c4;
                const float* fd = (const float*)d;
#pragma unroll
                for (int c = 0; c < NCH; ++c)
                    acc[c] = (fa[c] - fb[c] - fc[c] + fd[c]) * inv;
            }
#pragma unroll
            for (int off = 32; off; off >>= 1) {
#pragma unroll
                for (int c = 0; c < NCH; ++c) acc[c] += __shfl_down(acc[c], off, 64);
            }
            if (lane == 0) {
                const float k = 1.0f / 49.0f;
                float4* po = (float4*)(out + (size_t)roi * NCH);
                po[0] = make_float4(acc[0] * k, acc[1] * k, acc[2] * k, acc[3] * k);
                po[1] = make_float4(acc[4] * k, acc[5] * k, acc[6] * k, acc[7] * k);
            }
        }
    }
}

// ===================== fallback path: round-5 five kernels ==================
__global__ __launch_bounds__(256) void rowscan_kernel(const float* __restrict__ in,
                                                      float* __restrict__ sat) {
    const int y    = blockIdx.x;
    const int t    = threadIdx.x;
    const int lane = t & 63;
    const int wv   = t >> 6;
    __shared__ float lds[NCH][1024];
    for (int k = 0; k < 2; ++k) {
        const int c = wv * 2 + k;
        const float4* r4 = (const float4*)(in + ((size_t)c * 1024 + y) * 1024);
        double chunkbase = 0.0;
#pragma unroll
        for (int j = 0; j < 4; ++j) {
            float4 a = r4[lane + 64 * j];
            double v0 = a.x, v1 = a.y, v2 = a.z, v3 = a.w;
            double s = v0 + v1 + v2 + v3;
            double ps = s;
#pragma unroll
            for (int off = 1; off < 64; off <<= 1) {
                double n = __shfl_up(ps, off, 64);
                if (lane >= off) ps += n;
            }
            double base = chunkbase + ps - s;
            double p0 = base + v0, p1 = p0 + v1, p2 = p1 + v2, p3 = p2 + v3;
            ((float4*)lds[c])[lane + 64 * j] =
                make_float4((float)p0, (float)p1, (float)p2, (float)p3);
            chunkbase += __shfl(ps, 63, 64);
        }
    }
    __syncthreads();
    float* orow = sat + (size_t)(y + 1) * W8P;
    for (int f4 = t; f4 < W8P / 4; f4 += 256) {
        int f = f4 * 4;
        float4 o;
        float* po = (float*)&o;
#pragma unroll
        for (int j = 0; j < 4; ++j) {
            int ff = f + j;
            int x = ff >> 3, c = ff & 7;
            po[j] = (x >= 1 && x <= 1024) ? lds[c][x - 1] : 0.0f;
        }
        ((float4*)orow)[f4] = o;
    }
}

__global__ __launch_bounds__(256) void band_sum(const float* __restrict__ sat,
                                                double* __restrict__ bsum) {
    const int c = blockIdx.x, b = blockIdx.y, t = threadIdx.x;
    const int col0 = c * CHUNK_F32 + t * 4;
    if (col0 >= W8) return;
    const float* p = sat + (size_t)(1 + b * BROWS) * W8P + col0;
    double s0 = 0, s1 = 0, s2 = 0, s3 = 0;
#pragma unroll
    for (int k = 0; k < BROWS; ++k) {
        float4 v = *(const float4*)(p + (size_t)k * W8P);
        s0 += v.x; s1 += v.y; s2 += v.z; s3 += v.w;
    }
    double* o = bsum + (size_t)b * W8P + col0;
    double2 lo, hi; lo.x = s0; lo.y = s1; hi.x = s2; hi.y = s3;
    *(double2*)o = lo; *((double2*)o + 1) = hi;
}

__global__ __launch_bounds__(64) void band_prefix(double* __restrict__ bsum) {
    const int lane = threadIdx.x;
    const int rg = lane >> 3, s = lane & 7;
    const size_t base = (size_t)blockIdx.x * 16 + (size_t)s * 2;
    double2 v[8];
#pragma unroll
    for (int k = 0; k < 8; ++k)
        v[k] = *(const double2*)(bsum + (size_t)(rg * 8 + k) * W8P + base);
    double i0 = 0, i1 = 0; double incl0[8], incl1[8];
#pragma unroll
    for (int k = 0; k < 8; ++k) { i0 += v[k].x; i1 += v[k].y; incl0[k] = i0; incl1[k] = i1; }
    double a0 = i0, a1 = i1;
#pragma unroll
    for (int off = 8; off <= 32; off <<= 1) {
        double u0 = __shfl_up(a0, off, 64), u1 = __shfl_up(a1, off, 64);
        if (lane >= off) { a0 += u0; a1 += u1; }
    }
    const double b0 = a0 - i0, b1 = a1 - i1;
#pragma unroll
    for (int k = 0; k < 8; ++k) {
        double2 e; e.x = b0 + incl0[k] - v[k].x; e.y = b1 + incl1[k] - v[k].y;
        *(double2*)(bsum + (size_t)(rg * 8 + k) * W8P + base) = e;
    }
}

__global__ __launch_bounds__(256) void band_apply(float* __restrict__ sat,
                                                  const double* __restrict__ bpre) {
    const int c = blockIdx.x, b = blockIdx.y, t = threadIdx.x;
    const int col0 = c * CHUNK_F32 + t * 4;
    if (col0 >= W8) return;
    const double* q = bpre + (size_t)b * W8P + col0;
    double2 qlo = *(const double2*)q; double2 qhi = *((const double2*)q + 1);
    double a0 = qlo.x, a1 = qlo.y, a2 = qhi.x, a3 = qhi.y;
    float* p = sat + (size_t)(1 + b * BROWS) * W8P + col0;
    float4 v[BROWS];
#pragma unroll
    for (int k = 0; k < BROWS; ++k) v[k] = *(const float4*)(p + (size_t)k * W8P);
#pragma unroll
    for (int k = 0; k < BROWS; ++k) {
        a0 += v[k].x; a1 += v[k].y; a2 += v[k].z; a3 += v[k].w;
        *(float4*)(p + (size_t)k * W8P) =
            make_float4((float)a0, (float)a1, (float)a2, (float)a3);
    }
    if (b == 0) *(float4*)(sat + col0) = make_float4(0.f, 0.f, 0.f, 0.f);
}

__global__ __launch_bounds__(256) void pool_kernel(const float* __restrict__ sat,
                                                   const int* __restrict__ rois,
                                                   float* __restrict__ out,
                                                   int n_roi) {
    int lane = threadIdx.x & 63;
    int roi  = (blockIdx.x * blockDim.x + threadIdx.x) >> 6;
    if (roi >= n_roi) return;
    const int4 rv = ((const int4*)rois)[roi];
    int ymin = rv.x >> 5, xmin = rv.y >> 5;
    int Ly = (rv.z >> 5) + 1 - ymin, Lx = (rv.w >> 5) + 1 - xmin;
    float acc[NCH];
#pragma unroll
    for (int c = 0; c < NCH; ++c) acc[c] = 0.0f;
    if (lane < 49) {
        int by = lane / 7, bx = lane - by * 7;
        int ylo = ymin + (by * Ly) / 7, yhi = ymin + ((by + 1) * Ly + 6) / 7;
        int xlo = xmin + (bx * Lx) / 7, xhi = xmin + ((bx + 1) * Lx + 6) / 7;
        float inv = 1.0f / (float)((yhi - ylo) * (xhi - xlo));
        float4 a[2], b[2], c4[2], d[2];
        const float4* hh = (const float4*)(sat + ((size_t)yhi * SATW_PAD + xhi) * NCH);
        const float4* lh = (const float4*)(sat + ((size_t)ylo * SATW_PAD + xhi) * NCH);
        const float4* hl = (const float4*)(sat + ((size_t)yhi * SATW_PAD + xlo) * NCH);
        const float4* ll = (const float4*)(sat + ((size_t)ylo * SATW_PAD + xlo) * NCH);
        a[0] = hh[0]; a[1] = hh[1]; b[0] = lh[0]; b[1] = lh[1];
        c4[0] = hl[0]; c4[1] = hl[1]; d[0] = ll[0]; d[1] = ll[1];
        const float* fa = (const float*)a; const float* fb = (const float*)b;
        const float* fc = (const float*)c4; const float* fd = (const float*)d;
#pragma unroll
        for (int c = 0; c < NCH; ++c)
            acc[c] = (fa[c] - fb[c] - fc[c] + fd[c]) * inv;
    }
#pragma unroll
    for (int off = 32; off; off >>= 1) {
#pragma unroll
        for (int c = 0; c < NCH; ++c) acc[c] += __shfl_down(acc[c], off, 64);
    }
    if (lane == 0) {
        const float k = 1.0f / 49.0f;
        float4* po = (float4*)(out + (size_t)roi * NCH);
        po[0] = make_float4(acc[0] * k, acc[1] * k, acc[2] * k, acc[3] * k);
        po[1] = make_float4(acc[4] * k, acc[5] * k, acc[6] * k, acc[7] * k);
    }
}

// ============================== launcher ====================================
extern "C" void kernel_launch(void* const* d_in, const int* in_sizes, int n_in,
                              void* d_out, int out_size, void* d_ws, size_t ws_size,
                              hipStream_t stream) {
    const float* conv = (const float*)d_in[0];   // (1, 8, 1024, 1024) f32
    const int*   rois = (const int*)d_in[1];     // (8192, 4) int32
    float*       out  = (float*)d_out;           // (8192, 2, 4) f32 flat
    int n_roi = in_sizes[1] / 4;

    float*  sat  = (float*)d_ws;                          // 33.65 MB
    double* bsum = (double*)((char*)d_ws + 33652992);     // 64*8208*8 = 4.2 MB

    static int coop_grid = -1;                   // -1 unknown, 0 unusable
    if (coop_grid == -1) {
        int nb = 0;
        hipError_t e = hipOccupancyMaxActiveBlocksPerMultiprocessor(
            &nb, fused_sat_pool, 256, 0);
        if (e == hipSuccess && nb >= 1) {
            if (nb > 4) nb = 4;
            coop_grid = nb * 256;                // 256 CUs
        } else {
            coop_grid = 0;
        }
    }

    bool done = false;
    if (coop_grid > 0) {
        void* args[] = {(void*)&conv, (void*)&rois, (void*)&out,
                        (void*)&sat,  (void*)&bsum, (void*)&n_roi};
        hipError_t e = hipLaunchCooperativeKernel(
            (const void*)fused_sat_pool, dim3(coop_grid), dim3(256),
            args, 0, stream);
        if (e == hipSuccess) done = true;
        else coop_grid = 0;                      // don't retry next capture
    }

    if (!done) {                                 // round-5 fallback
        rowscan_kernel<<<1024, 256, 0, stream>>>(conv, sat);
        band_sum   <<<dim3(NCHUNK, NBAND), 256, 0, stream>>>(sat, bsum);
        band_prefix<<<513, 64, 0, stream>>>(bsum);
        band_apply <<<dim3(NCHUNK, NBAND), 256, 0, stream>>>(sat, bsum);
        pool_kernel<<<(n_roi + 3) / 4, 256, 0, stream>>>(sat, rois, out, n_roi);
    }
}

// Round 7
// 210.859 us; speedup vs baseline: 1.7604x; 1.7604x over previous
//
#include <hip/hip_runtime.h>
#include <cstddef>
#include <cstdint>

// ATTRIBUTION ROUND #3 — pin the fixed in-region cost F.
// Kernels byte-identical to the round-0 baseline (best known: 114.5us).
// The full A->B->C pipeline is executed THREE times (each pass recomputes
// from the inputs, so output/numerics are identical). With K = A+B+C:
//   dur1 = F + K = 114.5   (round 0)
//   dur3 = F + 3K          (this round)
//   =>  F = (3*114.5 - dur3) / 2
// Every round's trace shows a 256 MiB fillBufferAligned (~44us @ 6 TB/s) —
// the harness workspace re-poison. If F ~= 44, that fill is inside the timed
// region and all previous B-slot estimates were inflated by it.

#define SATW_PAD 1026
#define W8   8200          // used floats per y-row (1025 * 8)
#define W8P  8208          // padded floats per y-row (1026 * 8)
#define NCH  8
#define STRIP 16           // f32 columns per colscan block = one 64B line/row
#define NSTRIP (W8P / STRIP)   // 513, exact

// ---------------- Kernel A: row prefix sums, planar in -> interleaved out ----
__global__ __launch_bounds__(256) void rowscan_kernel(const float* __restrict__ in,
                                                      float* __restrict__ sat) {
    const int y    = blockIdx.x;
    const int t    = threadIdx.x;
    const int lane = t & 63;
    const int wv   = t >> 6;

    __shared__ float lds[NCH][1024];

    for (int k = 0; k < 2; ++k) {
        const int c = wv * 2 + k;
        const float4* r4 = (const float4*)(in + ((size_t)c * 1024 + y) * 1024);
        double chunkbase = 0.0;
#pragma unroll
        for (int j = 0; j < 4; ++j) {           // 4 chunks of 256 floats
            float4 a = r4[lane + 64 * j];       // coalesced per instruction
            double v0 = a.x, v1 = a.y, v2 = a.z, v3 = a.w;
            double s = v0 + v1 + v2 + v3;
            double ps = s;                      // inclusive scan of lane sums
#pragma unroll
            for (int off = 1; off < 64; off <<= 1) {
                double n = __shfl_up(ps, off, 64);
                if (lane >= off) ps += n;
            }
            double base = chunkbase + ps - s;   // exclusive prefix for this lane
            double p0 = base + v0, p1 = p0 + v1, p2 = p1 + v2, p3 = p2 + v3;
            ((float4*)lds[c])[lane + 64 * j] =
                make_float4((float)p0, (float)p1, (float)p2, (float)p3);
            chunkbase += __shfl(ps, 63, 64);    // chunk total broadcast
        }
    }
    __syncthreads();

    float* orow = sat + (size_t)(y + 1) * W8P;
    for (int f4 = t; f4 < W8P / 4; f4 += 256) {
        int f = f4 * 4;
        float4 o;
        float* po = (float*)&o;
#pragma unroll
        for (int j = 0; j < 4; ++j) {
            int ff = f + j;
            int x = ff >> 3, c = ff & 7;
            po[j] = (x >= 1 && x <= 1024) ? lds[c][x - 1] : 0.0f;
        }
        ((float4*)orow)[f4] = o;                // 64B-line-aligned store
    }
}

// ---------------- Kernel B: register-resident column scan (round-0 version) --
__global__ __launch_bounds__(256) void colscan_block(float* __restrict__ sat) {
    const int t    = threadIdx.x;
    const int lane = t & 63;
    const int w    = t >> 6;         // wave 0..3
    const int rg   = lane >> 2;      // row sub-chunk 0..15
    const int q    = lane & 3;       // float4 slot 0..3
    const int c0   = blockIdx.x * STRIP + q * 4;   // always < W8P, 16B-aligned

    float* p0 = sat + (size_t)(1 + w * 256 + rg * 16) * W8P + c0;

    float4 v[16];
#pragma unroll
    for (int k = 0; k < 16; ++k)
        v[k] = *(const float4*)(p0 + (size_t)k * W8P);

    double T0 = 0, T1 = 0, T2 = 0, T3 = 0;
#pragma unroll
    for (int k = 0; k < 16; ++k) {
        T0 += v[k].x; T1 += v[k].y; T2 += v[k].z; T3 += v[k].w;
    }

    double i0 = T0, i1 = T1, i2 = T2, i3 = T3;
#pragma unroll
    for (int s = 4; s <= 32; s <<= 1) {
        double a0 = __shfl_up(i0, s, 64), a1 = __shfl_up(i1, s, 64);
        double a2 = __shfl_up(i2, s, 64), a3 = __shfl_up(i3, s, 64);
        if (lane >= s) { i0 += a0; i1 += a1; i2 += a2; i3 += a3; }
    }
    double e0 = i0 - T0, e1 = i1 - T1, e2 = i2 - T2, e3 = i3 - T3;

    __shared__ double wt[4][4][4];   // [wave][q][comp] wave totals
    if (lane >= 60) {                // rg==15 lane holds the wave-inclusive total
        wt[w][q][0] = i0; wt[w][q][1] = i1; wt[w][q][2] = i2; wt[w][q][3] = i3;
    }
    __syncthreads();
    double b0 = e0, b1 = e1, b2 = e2, b3 = e3;
    for (int w2 = 0; w2 < w; ++w2) {
        b0 += wt[w2][q][0]; b1 += wt[w2][q][1];
        b2 += wt[w2][q][2]; b3 += wt[w2][q][3];
    }

#pragma unroll
    for (int k = 0; k < 16; ++k) {
        b0 += v[k].x; b1 += v[k].y; b2 += v[k].z; b3 += v[k].w;
        *(float4*)(p0 + (size_t)k * W8P) =
            make_float4((float)b0, (float)b1, (float)b2, (float)b3);
    }

    if (t < 4) {
        int cz = blockIdx.x * STRIP + t * 4;
        *(float4*)(sat + cz) = make_float4(0.f, 0.f, 0.f, 0.f);
    }
}

// ---------------- Kernel C: one wave per ROI, all 8 channels (f32 math) ------
__global__ __launch_bounds__(256) void pool_kernel(const float* __restrict__ sat,
                                                   const int* __restrict__ rois,
                                                   float* __restrict__ out,
                                                   int n_roi) {
    int lane = threadIdx.x & 63;
    int roi  = (blockIdx.x * blockDim.x + threadIdx.x) >> 6;
    if (roi >= n_roi) return;

    const int4 rv = ((const int4*)rois)[roi];   // [y0, x0, y1, x1] pixel coords
    int ymin = rv.x >> 5;                       // / FEAT_STRIDE(32)
    int xmin = rv.y >> 5;
    int Ly   = (rv.z >> 5) + 1 - ymin;
    int Lx   = (rv.w >> 5) + 1 - xmin;

    float acc[NCH];
#pragma unroll
    for (int c = 0; c < NCH; ++c) acc[c] = 0.0f;

    if (lane < 49) {
        int by = lane / 7;
        int bx = lane - by * 7;
        int ylo = ymin + (by * Ly) / 7;
        int yhi = ymin + ((by + 1) * Ly + 6) / 7;
        int xlo = xmin + (bx * Lx) / 7;
        int xhi = xmin + ((bx + 1) * Lx + 6) / 7;
        float inv = 1.0f / (float)((yhi - ylo) * (xhi - xlo));

        float4 a[2], b[2], c4[2], d[2];
        const float4* hh = (const float4*)(sat + ((size_t)yhi * SATW_PAD + xhi) * NCH);
        const float4* lh = (const float4*)(sat + ((size_t)ylo * SATW_PAD + xhi) * NCH);
        const float4* hl = (const float4*)(sat + ((size_t)yhi * SATW_PAD + xlo) * NCH);
        const float4* ll = (const float4*)(sat + ((size_t)ylo * SATW_PAD + xlo) * NCH);
        a[0] = hh[0]; a[1] = hh[1];
        b[0] = lh[0]; b[1] = lh[1];
        c4[0] = hl[0]; c4[1] = hl[1];
        d[0] = ll[0]; d[1] = ll[1];
        const float* fa = (const float*)a;
        const float* fb = (const float*)b;
        const float* fc = (const float*)c4;
        const float* fd = (const float*)d;
#pragma unroll
        for (int c = 0; c < NCH; ++c)
            acc[c] = (fa[c] - fb[c] - fc[c] + fd[c]) * inv;
    }

#pragma unroll
    for (int off = 32; off; off >>= 1) {
#pragma unroll
        for (int c = 0; c < NCH; ++c) acc[c] += __shfl_down(acc[c], off, 64);
    }

    if (lane == 0) {
        const float k = 1.0f / 49.0f;
        float4* po = (float4*)(out + (size_t)roi * NCH);
        po[0] = make_float4(acc[0] * k, acc[1] * k, acc[2] * k, acc[3] * k);
        po[1] = make_float4(acc[4] * k, acc[5] * k, acc[6] * k, acc[7] * k);
    }
}

extern "C" void kernel_launch(void* const* d_in, const int* in_sizes, int n_in,
                              void* d_out, int out_size, void* d_ws, size_t ws_size,
                              hipStream_t stream) {
    const float* conv = (const float*)d_in[0];   // (1, 8, 1024, 1024) f32
    const int*   rois = (const int*)d_in[1];     // (8192, 4) int32
    float*       out  = (float*)d_out;           // (8192, 2, 4) f32 flat
    int n_roi = in_sizes[1] / 4;

    float* sat = (float*)d_ws;                   // 1025 * 8208 * 4 = 33.65 MB

    // ---- full pipeline x3 (each pass recomputes from inputs) ----
    for (int rep = 0; rep < 3; ++rep) {
        rowscan_kernel<<<1024, 256, 0, stream>>>(conv, sat);
        colscan_block<<<NSTRIP, 256, 0, stream>>>(sat);
        pool_kernel<<<(n_roi + 3) / 4, 256, 0, stream>>>(sat, rois, out, n_roi);
    }
}

// Round 8
// 116.241 us; speedup vs baseline: 3.1933x; 1.8140x over previous
//
#include <hip/hip_runtime.h>
#include <cstddef>
#include <cstdint>

// SAT layout: channel-interleaved, line-aligned, PER-ROW LINE-XOR SWIZZLED.
// Logical: sat[(r*1026 + x)*8 + c], r,x in [0,1025), c in [0,8).
// Row stride 1026*8 f32 = 32832 B = 513 64B lines (lines 0..512 per row).
// Physical line within row: P(r,l) = l<512 ? l ^ (r & 511) : 512.
//
// WHY (round 8): attribution rounds pinned F=66us fixed in-region overhead,
// K=48.2us kernel work (A=11.9 floor, C=16.6, B=19.7 vs ~11 floor). B's
// columnar walk at stride 32832 B advances channel/L3-slice index by an even
// stride at any interleave granule >=256B (128.25 granules / 8.016 pages per
// row) -> ~1/8..1/32 channel coverage -> 3.4 TB/s warm (0.8 cold). The XOR
// scrambles the low 9 line bits per row: full coverage, zero extra traffic,
// bit-identical arithmetic. A's stores stay dense (16-line blocks map to
// permuted full 1KB blocks). C pays ~3 VALU per corner.

#define SATW_PAD 1026
#define W8   8200          // used floats per row (1025 * 8)
#define W8P  8208          // padded floats per row (1026 * 8) = 513 lines
#define NCH  8
#define NSTRIP 513         // one block per 64B line-column

__device__ __forceinline__ int swz_line(int r, int l) {
    return (l < 512) ? (l ^ (r & 511)) : 512;
}

// ---------------- Kernel A: row prefix sums, planar in -> interleaved out ----
__global__ __launch_bounds__(256) void rowscan_kernel(const float* __restrict__ in,
                                                      float* __restrict__ sat) {
    const int y    = blockIdx.x;
    const int t    = threadIdx.x;
    const int lane = t & 63;
    const int wv   = t >> 6;

    __shared__ float lds[NCH][1024];

    for (int k = 0; k < 2; ++k) {
        const int c = wv * 2 + k;
        const float4* r4 = (const float4*)(in + ((size_t)c * 1024 + y) * 1024);
        double chunkbase = 0.0;
#pragma unroll
        for (int j = 0; j < 4; ++j) {           // 4 chunks of 256 floats
            float4 a = r4[lane + 64 * j];       // coalesced per instruction
            double v0 = a.x, v1 = a.y, v2 = a.z, v3 = a.w;
            double s = v0 + v1 + v2 + v3;
            double ps = s;                      // inclusive scan of lane sums
#pragma unroll
            for (int off = 1; off < 64; off <<= 1) {
                double n = __shfl_up(ps, off, 64);
                if (lane >= off) ps += n;
            }
            double base = chunkbase + ps - s;   // exclusive prefix for this lane
            double p0 = base + v0, p1 = p0 + v1, p2 = p1 + v2, p3 = p2 + v3;
            ((float4*)lds[c])[lane + 64 * j] =
                make_float4((float)p0, (float)p1, (float)p2, (float)p3);
            chunkbase += __shfl(ps, 63, 64);    // chunk total broadcast
        }
    }
    __syncthreads();

    // Interleaved row write with line swizzle. flat f -> x=f>>3, c=f&7;
    // val = (1<=x<=1024) ? prefix[x-1] : 0. Each float4 stays inside one
    // 16-f32 line, so only the line index is permuted.
    const int r   = y + 1;
    const int key = r & 511;
    float* orow = sat + (size_t)r * W8P;
    for (int f4 = t; f4 < W8P / 4; f4 += 256) {
        int f = f4 * 4;
        float4 o;
        float* po = (float*)&o;
#pragma unroll
        for (int j = 0; j < 4; ++j) {
            int ff = f + j;
            int x = ff >> 3, c = ff & 7;
            po[j] = (x >= 1 && x <= 1024) ? lds[c][x - 1] : 0.0f;
        }
        int l  = f >> 4;                        // logical line 0..512
        int pl = (l < 512) ? (l ^ key) : 512;
        *(float4*)(orow + pl * 16 + (f & 15)) = o;
    }
}

// ---------------- Kernel B: register-resident column scan --------------------
// One 256-thread block owns one logical 64B line-column for the full 1024-row
// height in registers (16 float4/lane). Wave w: rows [256w, 256w+256). Lane
// (rg,q): rg=lane>>2 owns rows 256w+16rg..+15 at float4 slot q=lane&3.
// Addresses apply the per-row line swizzle: full channel/slice coverage.
__global__ __launch_bounds__(256) void colscan_block(float* __restrict__ sat) {
    const int t    = threadIdx.x;
    const int lane = t & 63;
    const int w    = t >> 6;         // wave 0..3
    const int rg   = lane >> 2;      // row sub-chunk 0..15
    const int q    = lane & 3;       // float4 slot 0..3
    const int ell  = blockIdx.x;     // logical line 0..512

    const int r0 = 1 + w * 256 + rg * 16;

    float4 v[16];
#pragma unroll
    for (int k = 0; k < 16; ++k) {
        int r = r0 + k;
        v[k] = *(const float4*)(sat + (size_t)r * W8P + swz_line(r, ell) * 16 + q * 4);
    }

    // per-lane f64 totals over its 16 contiguous rows
    double T0 = 0, T1 = 0, T2 = 0, T3 = 0;
#pragma unroll
    for (int k = 0; k < 16; ++k) {
        T0 += v[k].x; T1 += v[k].y; T2 += v[k].z; T3 += v[k].w;
    }

    // in-wave inclusive scan over rg (lanes with same q are 4 apart)
    double i0 = T0, i1 = T1, i2 = T2, i3 = T3;
#pragma unroll
    for (int s = 4; s <= 32; s <<= 1) {
        double a0 = __shfl_up(i0, s, 64), a1 = __shfl_up(i1, s, 64);
        double a2 = __shfl_up(i2, s, 64), a3 = __shfl_up(i3, s, 64);
        if (lane >= s) { i0 += a0; i1 += a1; i2 += a2; i3 += a3; }
    }
    double e0 = i0 - T0, e1 = i1 - T1, e2 = i2 - T2, e3 = i3 - T3;

    __shared__ double wt[4][4][4];   // [wave][q][comp] wave totals
    if (lane >= 60) {                // rg==15 lane holds the wave-inclusive total
        wt[w][q][0] = i0; wt[w][q][1] = i1; wt[w][q][2] = i2; wt[w][q][3] = i3;
    }
    __syncthreads();
    double b0 = e0, b1 = e1, b2 = e2, b3 = e3;
    for (int w2 = 0; w2 < w; ++w2) {
        b0 += wt[w2][q][0]; b1 += wt[w2][q][1];
        b2 += wt[w2][q][2]; b3 += wt[w2][q][3];
    }

#pragma unroll
    for (int k = 0; k < 16; ++k) {
        int r = r0 + k;
        b0 += v[k].x; b1 += v[k].y; b2 += v[k].z; b3 += v[k].w;
        *(float4*)(sat + (size_t)r * W8P + swz_line(r, ell) * 16 + q * 4) =
            make_float4((float)b0, (float)b1, (float)b2, (float)b3);
    }

    // SAT row r=0 is zeros for this line (row 0 key = 0 -> identity mapping)
    if (t < 4) {
        *(float4*)(sat + (size_t)ell * 16 + t * 4) =
            make_float4(0.f, 0.f, 0.f, 0.f);
    }
}

// ---------------- Kernel C: one wave per ROI, all 8 channels (f32 math) ------
// Lane<49 owns one 7x7 bin: 4 corners x 8 interleaved channels (2 float4 each).
// Corner (r, x): logical line = x>>1 (guarded identity at x==1024), 8-channel
// block = 32B at half-line offset (x&1)*8 — always inside one line.
__global__ __launch_bounds__(256) void pool_kernel(const float* __restrict__ sat,
                                                   const int* __restrict__ rois,
                                                   float* __restrict__ out,
                                                   int n_roi) {
    int lane = threadIdx.x & 63;
    int roi  = (blockIdx.x * blockDim.x + threadIdx.x) >> 6;
    if (roi >= n_roi) return;

    const int4 rv = ((const int4*)rois)[roi];   // [y0, x0, y1, x1] pixel coords
    int ymin = rv.x >> 5;                       // / FEAT_STRIDE(32)
    int xmin = rv.y >> 5;
    int Ly   = (rv.z >> 5) + 1 - ymin;
    int Lx   = (rv.w >> 5) + 1 - xmin;

    float acc[NCH];
#pragma unroll
    for (int c = 0; c < NCH; ++c) acc[c] = 0.0f;

    if (lane < 49) {
        int by = lane / 7;
        int bx = lane - by * 7;
        int ylo = ymin + (by * Ly) / 7;
        int yhi = ymin + ((by + 1) * Ly + 6) / 7;
        int xlo = xmin + (bx * Lx) / 7;
        int xhi = xmin + ((bx + 1) * Lx + 6) / 7;
        float inv = 1.0f / (float)((yhi - ylo) * (xhi - xlo));

        auto coff = [&](int r, int x) -> size_t {
            int l = x >> 1;
            int pl = (l < 512) ? (l ^ (r & 511)) : 512;
            return (size_t)r * W8P + (size_t)pl * 16 + ((x & 1) << 3);
        };

        float4 a[2], b[2], c4[2], d[2];
        const float4* hh = (const float4*)(sat + coff(yhi, xhi));
        const float4* lh = (const float4*)(sat + coff(ylo, xhi));
        const float4* hl = (const float4*)(sat + coff(yhi, xlo));
        const float4* ll = (const float4*)(sat + coff(ylo, xlo));
        a[0] = hh[0]; a[1] = hh[1];
        b[0] = lh[0]; b[1] = lh[1];
        c4[0] = hl[0]; c4[1] = hl[1];
        d[0] = ll[0]; d[1] = ll[1];
        const float* fa = (const float*)a;
        const float* fb = (const float*)b;
        const float* fc = (const float*)c4;
        const float* fd = (const float*)d;
#pragma unroll
        for (int c = 0; c < NCH; ++c)
            acc[c] = (fa[c] - fb[c] - fc[c] + fd[c]) * inv;
    }

#pragma unroll
    for (int off = 32; off; off >>= 1) {
#pragma unroll
        for (int c = 0; c < NCH; ++c) acc[c] += __shfl_down(acc[c], off, 64);
    }

    if (lane == 0) {
        const float k = 1.0f / 49.0f;
        float4* po = (float4*)(out + (size_t)roi * NCH);
        po[0] = make_float4(acc[0] * k, acc[1] * k, acc[2] * k, acc[3] * k);
        po[1] = make_float4(acc[4] * k, acc[5] * k, acc[6] * k, acc[7] * k);
    }
}

extern "C" void kernel_launch(void* const* d_in, const int* in_sizes, int n_in,
                              void* d_out, int out_size, void* d_ws, size_t ws_size,
                              hipStream_t stream) {
    const float* conv = (const float*)d_in[0];   // (1, 8, 1024, 1024) f32
    const int*   rois = (const int*)d_in[1];     // (8192, 4) int32
    float*       out  = (float*)d_out;           // (8192, 2, 4) f32 flat
    int n_roi = in_sizes[1] / 4;

    float* sat = (float*)d_ws;                   // 1025 * 8208 * 4 = 33.65 MB

    rowscan_kernel<<<1024, 256, 0, stream>>>(conv, sat);
    colscan_block<<<NSTRIP, 256, 0, stream>>>(sat);
    pool_kernel<<<(n_roi + 3) / 4, 256, 0, stream>>>(sat, rois, out, n_roi);
}

// Round 9
// 114.990 us; speedup vs baseline: 3.2280x; 1.0109x over previous
//
#include <hip/hip_runtime.h>
#include <cstddef>
#include <cstdint>

// FINAL (revert to round-0 best: 114.5us measured).
// Session ledger (attribution rounds 2/3/7): F=66.3us fixed in-region
// overhead (256MiB workspace re-poison fill ~44us + ~22us harness), A=11.9
// (at ~66MB traffic floor), B=19.7 warm (scattered-RMW class ceiling:
// occupancy[r1], per-instr contiguity[r5], line-XOR channel swizzle[r8] all
// refuted as levers), C=16.6 (LLC-latency bound at full occupancy).
// Remaining structural fix for B (single-pass chained scan with vector
// lookback) costs >= its ~5us upside and requires dispatch-order/spin
// assumptions (Guideline 16) — rejected.

// Channel-interleaved, LINE-ALIGNED SAT: sat[(y*1026 + x)*8 + c], y,x in
// [0,1025), c in [0,8). Row stride = 1026*8 f32 = 32832 B = 513 full 64B
// lines (the unpadded 32800 B stride is NOT 64B-aligned: alternate rows
// line-split every 64B segment and false-share lines across blocks/XCDs).
#define SATW_PAD 1026
#define W8   8200          // used floats per y-row (1025 * 8)
#define W8P  8208          // padded floats per y-row (1026 * 8)
#define NCH  8
#define STRIP 16           // f32 columns per colscan block = one 64B line/row
#define NSTRIP (W8P / STRIP)   // 513, exact

// ---------------- Kernel A: row prefix sums, planar in -> interleaved out ----
// One block per y. 4 waves; wave w scans channels 2w and 2w+1 independently
// (chunked wave scan, f64 accumulate), stages to LDS, then a fully-coalesced
// line-aligned float4 write of the interleaved row.
__global__ __launch_bounds__(256) void rowscan_kernel(const float* __restrict__ in,
                                                      float* __restrict__ sat) {
    const int y    = blockIdx.x;
    const int t    = threadIdx.x;
    const int lane = t & 63;
    const int wv   = t >> 6;

    __shared__ float lds[NCH][1024];

    for (int k = 0; k < 2; ++k) {
        const int c = wv * 2 + k;
        const float4* r4 = (const float4*)(in + ((size_t)c * 1024 + y) * 1024);
        double chunkbase = 0.0;
#pragma unroll
        for (int j = 0; j < 4; ++j) {           // 4 chunks of 256 floats
            float4 a = r4[lane + 64 * j];       // coalesced per instruction
            double v0 = a.x, v1 = a.y, v2 = a.z, v3 = a.w;
            double s = v0 + v1 + v2 + v3;
            double ps = s;                      // inclusive scan of lane sums
#pragma unroll
            for (int off = 1; off < 64; off <<= 1) {
                double n = __shfl_up(ps, off, 64);
                if (lane >= off) ps += n;
            }
            double base = chunkbase + ps - s;   // exclusive prefix for this lane
            double p0 = base + v0, p1 = p0 + v1, p2 = p1 + v2, p3 = p2 + v3;
            ((float4*)lds[c])[lane + 64 * j] =
                make_float4((float)p0, (float)p1, (float)p2, (float)p3);
            chunkbase += __shfl(ps, 63, 64);    // chunk total broadcast
        }
    }
    __syncthreads();

    // Interleaved row write: flat f -> x = f>>3, c = f&7;
    // val = (1<=x<=1024) ? prefix[x-1] : 0 (x==0 boundary, x==1025 pad)
    float* orow = sat + (size_t)(y + 1) * W8P;
    for (int f4 = t; f4 < W8P / 4; f4 += 256) {
        int f = f4 * 4;
        float4 o;
        float* po = (float*)&o;
#pragma unroll
        for (int j = 0; j < 4; ++j) {
            int ff = f + j;
            int x = ff >> 3, c = ff & 7;
            po[j] = (x >= 1 && x <= 1024) ? lds[c][x - 1] : 0.0f;
        }
        ((float4*)orow)[f4] = o;                // 64B-line-aligned store
    }
}

// ---------------- Kernel B: register-resident column scan --------------------
// One 256-thread block owns a 16-f32-column strip (= one private 64B line per
// row, no cross-block line sharing) for the FULL 1024-row height in registers
// (16 float4/lane). Wave w: rows [256w, 256w+256). Lane (rg,q): rg=lane>>2
// owns rows 256w+16rg..+15 at float4 slot q=lane&3. Phase 1: 16 independent
// 16B loads (ILP). Phase 2: per-lane f64 sum, 4-step shuffle scan over rg,
// tiny LDS scan over 4 waves. Phase 3: re-walk registers add f64 base, store.
__global__ __launch_bounds__(256) void colscan_block(float* __restrict__ sat) {
    const int t    = threadIdx.x;
    const int lane = t & 63;
    const int w    = t >> 6;         // wave 0..3
    const int rg   = lane >> 2;      // row sub-chunk 0..15
    const int q    = lane & 3;       // float4 slot 0..3
    const int c0   = blockIdx.x * STRIP + q * 4;   // always < W8P, 16B-aligned

    float* p0 = sat + (size_t)(1 + w * 256 + rg * 16) * W8P + c0;

    float4 v[16];
#pragma unroll
    for (int k = 0; k < 16; ++k)
        v[k] = *(const float4*)(p0 + (size_t)k * W8P);

    // per-lane f64 totals over its 16 contiguous rows
    double T0 = 0, T1 = 0, T2 = 0, T3 = 0;
#pragma unroll
    for (int k = 0; k < 16; ++k) {
        T0 += v[k].x; T1 += v[k].y; T2 += v[k].z; T3 += v[k].w;
    }

    // in-wave inclusive scan over rg (lanes with same q are 4 apart)
    double i0 = T0, i1 = T1, i2 = T2, i3 = T3;
#pragma unroll
    for (int s = 4; s <= 32; s <<= 1) {
        double a0 = __shfl_up(i0, s, 64), a1 = __shfl_up(i1, s, 64);
        double a2 = __shfl_up(i2, s, 64), a3 = __shfl_up(i3, s, 64);
        if (lane >= s) { i0 += a0; i1 += a1; i2 += a2; i3 += a3; }
    }
    double e0 = i0 - T0, e1 = i1 - T1, e2 = i2 - T2, e3 = i3 - T3;

    __shared__ double wt[4][4][4];   // [wave][q][comp] wave totals
    if (lane >= 60) {                // rg==15 lane holds the wave-inclusive total
        wt[w][q][0] = i0; wt[w][q][1] = i1; wt[w][q][2] = i2; wt[w][q][3] = i3;
    }
    __syncthreads();
    double b0 = e0, b1 = e1, b2 = e2, b3 = e3;
    for (int w2 = 0; w2 < w; ++w2) {
        b0 += wt[w2][q][0]; b1 += wt[w2][q][1];
        b2 += wt[w2][q][2]; b3 += wt[w2][q][3];
    }

#pragma unroll
    for (int k = 0; k < 16; ++k) {
        b0 += v[k].x; b1 += v[k].y; b2 += v[k].z; b3 += v[k].w;
        *(float4*)(p0 + (size_t)k * W8P) =
            make_float4((float)b0, (float)b1, (float)b2, (float)b3);
    }

    // SAT row y=0 is zeros for this strip
    if (t < 4) {
        int cz = blockIdx.x * STRIP + t * 4;
        *(float4*)(sat + cz) = make_float4(0.f, 0.f, 0.f, 0.f);
    }
}

// ---------------- Kernel C: one wave per ROI, all 8 channels (f32 math) ------
// Lane<49 owns one 7x7 bin: 4 corners x 8 interleaved channels (2 float4 each).
// Adaptive bins OVERLAP (hi_b = ceil vs lo_{b+1} = floor), so the 196 corner
// points (14x14 boundary grid) are genuinely distinct — loads are at the floor.
__global__ __launch_bounds__(256) void pool_kernel(const float* __restrict__ sat,
                                                   const int* __restrict__ rois,
                                                   float* __restrict__ out,
                                                   int n_roi) {
    int lane = threadIdx.x & 63;
    int roi  = (blockIdx.x * blockDim.x + threadIdx.x) >> 6;
    if (roi >= n_roi) return;

    const int4 rv = ((const int4*)rois)[roi];   // [y0, x0, y1, x1] pixel coords
    int ymin = rv.x >> 5;                       // / FEAT_STRIDE(32)
    int xmin = rv.y >> 5;
    int Ly   = (rv.z >> 5) + 1 - ymin;
    int Lx   = (rv.w >> 5) + 1 - xmin;

    float acc[NCH];
#pragma unroll
    for (int c = 0; c < NCH; ++c) acc[c] = 0.0f;

    if (lane < 49) {
        int by = lane / 7;
        int bx = lane - by * 7;
        int ylo = ymin + (by * Ly) / 7;
        int yhi = ymin + ((by + 1) * Ly + 6) / 7;
        int xlo = xmin + (bx * Lx) / 7;
        int xhi = xmin + ((bx + 1) * Lx + 6) / 7;
        float inv = 1.0f / (float)((yhi - ylo) * (xhi - xlo));

        float4 a[2], b[2], c4[2], d[2];
        const float4* hh = (const float4*)(sat + ((size_t)yhi * SATW_PAD + xhi) * NCH);
        const float4* lh = (const float4*)(sat + ((size_t)ylo * SATW_PAD + xhi) * NCH);
        const float4* hl = (const float4*)(sat + ((size_t)yhi * SATW_PAD + xlo) * NCH);
        const float4* ll = (const float4*)(sat + ((size_t)ylo * SATW_PAD + xlo) * NCH);
        a[0] = hh[0]; a[1] = hh[1];
        b[0] = lh[0]; b[1] = lh[1];
        c4[0] = hl[0]; c4[1] = hl[1];
        d[0] = ll[0]; d[1] = ll[1];
        const float* fa = (const float*)a;
        const float* fb = (const float*)b;
        const float* fc = (const float*)c4;
        const float* fd = (const float*)d;
#pragma unroll
        for (int c = 0; c < NCH; ++c)
            acc[c] = (fa[c] - fb[c] - fc[c] + fd[c]) * inv;
    }

#pragma unroll
    for (int off = 32; off; off >>= 1) {
#pragma unroll
        for (int c = 0; c < NCH; ++c) acc[c] += __shfl_down(acc[c], off, 64);
    }

    if (lane == 0) {
        const float k = 1.0f / 49.0f;
        float4* po = (float4*)(out + (size_t)roi * NCH);
        po[0] = make_float4(acc[0] * k, acc[1] * k, acc[2] * k, acc[3] * k);
        po[1] = make_float4(acc[4] * k, acc[5] * k, acc[6] * k, acc[7] * k);
    }
}

extern "C" void kernel_launch(void* const* d_in, const int* in_sizes, int n_in,
                              void* d_out, int out_size, void* d_ws, size_t ws_size,
                              hipStream_t stream) {
    const float* conv = (const float*)d_in[0];   // (1, 8, 1024, 1024) f32
    const int*   rois = (const int*)d_in[1];     // (8192, 4) int32
    float*       out  = (float*)d_out;           // (8192, 2, 4) f32 flat
    int n_roi = in_sizes[1] / 4;

    float* sat = (float*)d_ws;                   // 1025 * 8208 * 4 = 33.65 MB

    rowscan_kernel<<<1024, 256, 0, stream>>>(conv, sat);
    colscan_block<<<NSTRIP, 256, 0, stream>>>(sat);
    pool_kernel<<<(n_roi + 3) / 4, 256, 0, stream>>>(sat, rois, out, n_roi);
}